// Round 1
// baseline (2380.798 us; speedup 1.0000x reference)
//
#include <hip/hip_runtime.h>
#include <cstdint>

#define B_    2
#define T_    1024
#define E_    1024
#define H_    16
#define HS_   64
#define L_    4
#define V_    32000
#define FF_   4096
#define BT_   2048
#define EPS_  1e-5f
#define SCALE_ 0.03125f   // 1/sqrt(E) = 1/32

typedef __bf16 bf16;
typedef bf16  bf16x4 __attribute__((ext_vector_type(4)));
typedef bf16  bf16x8 __attribute__((ext_vector_type(8)));
typedef float f32x4  __attribute__((ext_vector_type(4)));

// ---------------------------------------------------------------- embed
__global__ __launch_bounds__(256) void embed_kernel(
    const int* __restrict__ ids, const float* __restrict__ emb,
    const float* __restrict__ pos, float* __restrict__ x)
{
  int bt = blockIdx.x;
  int t  = bt & (T_ - 1);
  int id = ids[bt];
  f32x4 e = *(const f32x4*)(emb + (size_t)id * E_ + threadIdx.x * 4);
  f32x4 p = *(const f32x4*)(pos + (size_t)t  * E_ + threadIdx.x * 4);
  *(f32x4*)(x + (size_t)bt * E_ + threadIdx.x * 4) = e + p;
}

// ---------------------------------------------------------------- layernorm
__device__ __forceinline__ float wred_sum(float v) {
#pragma unroll
  for (int o = 32; o; o >>= 1) v += __shfl_xor(v, o, 64);
  return v;
}

__global__ __launch_bounds__(256) void ln_kernel(
    const float* __restrict__ x, const float* __restrict__ g,
    const float* __restrict__ b, float* __restrict__ h)
{
  int row = blockIdx.x, tid = threadIdx.x;
  f32x4 v = *(const f32x4*)(x + (size_t)row * E_ + tid * 4);
  float s  = v[0] + v[1] + v[2] + v[3];
  float sq = v[0]*v[0] + v[1]*v[1] + v[2]*v[2] + v[3]*v[3];
  s  = wred_sum(s);
  sq = wred_sum(sq);
  __shared__ float rs[4], rq[4];
  int w = tid >> 6, lane = tid & 63;
  if (lane == 0) { rs[w] = s; rq[w] = sq; }
  __syncthreads();
  float S = rs[0] + rs[1] + rs[2] + rs[3];
  float Q = rq[0] + rq[1] + rq[2] + rq[3];
  float mean = S * (1.0f / E_);
  float var  = Q * (1.0f / E_) - mean * mean;
  float rstd = rsqrtf(fmaxf(var, 0.0f) + EPS_);
  f32x4 gv = *(const f32x4*)(g + tid * 4);
  f32x4 bv = *(const f32x4*)(b + tid * 4);
  f32x4 o = (v - mean) * rstd * gv + bv;
  *(f32x4*)(h + (size_t)row * E_ + tid * 4) = o;
}

// ---------------------------------------------------------------- GEMM (bf16 MFMA)
// LDS tiles As[128][32], Bst[128][32] bf16 (row = 64B). XOR swizzle on byte
// offset: key = ((row>>1)&7)<<4 -> conflict-free b128 fragment reads,
// ~2-way staging writes. B is staged TRANSPOSED ([n][k]) via per-thread
// k-strided scalar f32 loads (coalesced across lanes along n).
#define SWZ(row, kbyte) ((((row) << 6) + (kbyte)) ^ ((((row) >> 1) & 7) << 4))

__device__ __forceinline__ void st4bf(void* p, float a, float b, float c, float d) {
  bf16x4 t = { (bf16)a, (bf16)b, (bf16)c, (bf16)d };
  *(bf16x4*)p = t;
}

template <int ACT, int RES>   // ACT: 0 none, 1 exact GELU.  RES: += residual
__global__ __launch_bounds__(256) void gemm_kernel(
    const float* __restrict__ A,
    const float* __restrict__ Bm0, const float* __restrict__ Bm1, const float* __restrict__ Bm2,
    const float* __restrict__ bi0, const float* __restrict__ bi1, const float* __restrict__ bi2,
    float* __restrict__ C0, float* __restrict__ C1, float* __restrict__ C2,
    const float* __restrict__ R0, const float* __restrict__ R1, const float* __restrict__ R2,
    int M, int N, int K)
{
  int z = blockIdx.z;
  const float* Bm = (z == 0) ? Bm0 : (z == 1) ? Bm1 : Bm2;
  const float* bi = (z == 0) ? bi0 : (z == 1) ? bi1 : bi2;
  float*       C  = (z == 0) ? C0  : (z == 1) ? C1  : C2;
  const float* R  = (z == 0) ? R0  : (z == 1) ? R1  : R2;

  __shared__ __align__(16) char As[128 * 32 * 2];
  __shared__ __align__(16) char Bs[128 * 32 * 2];

  int tid = threadIdx.x;
  int bm = blockIdx.y * 128;
  int bn = blockIdx.x * 128;

  // A staging: row = p*32 + tid/8 , float4 at k = (tid%8)*4
  int ar  = tid >> 3;
  int akq = tid & 7;
  // B staging: n = tid%128 , k half = tid/128 (16 k-values each, scalar loads)
  int bnn = tid & 127;
  int bkh = tid >> 7;

  f32x4 aR[4];
  float bR[16];

  int NT = K >> 5;

  // prefetch tile 0
#pragma unroll
  for (int p = 0; p < 4; ++p)
    aR[p] = *(const f32x4*)(A + (size_t)(bm + p * 32 + ar) * K + akq * 4);
#pragma unroll
  for (int p = 0; p < 4; ++p)
#pragma unroll
    for (int j = 0; j < 4; ++j)
      bR[p * 4 + j] = Bm[(size_t)(bkh * 16 + p * 4 + j) * N + bn + bnn];

  f32x4 acc[4][4];
#pragma unroll
  for (int i = 0; i < 4; ++i)
#pragma unroll
    for (int j = 0; j < 4; ++j) acc[i][j] = (f32x4){0.f, 0.f, 0.f, 0.f};

  int lane = tid & 63;
  int wid  = tid >> 6;
  int wm = (wid >> 1) * 64, wn = (wid & 1) * 64;
  int fr = lane & 15, fb = lane >> 4;

  for (int t = 0; t < NT; ++t) {
    __syncthreads();
#pragma unroll
    for (int p = 0; p < 4; ++p)
      st4bf(As + SWZ(p * 32 + ar, akq * 8), aR[p][0], aR[p][1], aR[p][2], aR[p][3]);
#pragma unroll
    for (int p = 0; p < 4; ++p)
      st4bf(Bs + SWZ(bnn, (bkh * 4 + p) * 8), bR[p * 4 + 0], bR[p * 4 + 1], bR[p * 4 + 2], bR[p * 4 + 3]);
    __syncthreads();

    if (t + 1 < NT) {
      int k0 = (t + 1) << 5;
#pragma unroll
      for (int p = 0; p < 4; ++p)
        aR[p] = *(const f32x4*)(A + (size_t)(bm + p * 32 + ar) * K + k0 + akq * 4);
#pragma unroll
      for (int p = 0; p < 4; ++p)
#pragma unroll
        for (int j = 0; j < 4; ++j)
          bR[p * 4 + j] = Bm[(size_t)(k0 + bkh * 16 + p * 4 + j) * N + bn + bnn];
    }

    bf16x8 af[4], bfr[4];
#pragma unroll
    for (int i = 0; i < 4; ++i)
      af[i] = *(const bf16x8*)(As + SWZ(wm + i * 16 + fr, fb * 16));
#pragma unroll
    for (int j = 0; j < 4; ++j)
      bfr[j] = *(const bf16x8*)(Bs + SWZ(wn + j * 16 + fr, fb * 16));
#pragma unroll
    for (int i = 0; i < 4; ++i)
#pragma unroll
      for (int j = 0; j < 4; ++j)
        acc[i][j] = __builtin_amdgcn_mfma_f32_16x16x32_bf16(af[i], bfr[j], acc[i][j], 0, 0, 0);
  }

  // epilogue: C/D layout col = lane&15, row = (lane>>4)*4 + reg
#pragma unroll
  for (int i = 0; i < 4; ++i) {
#pragma unroll
    for (int j = 0; j < 4; ++j) {
      int gc = bn + wn + j * 16 + fr;
      float bv = bi[gc];
#pragma unroll
      for (int r = 0; r < 4; ++r) {
        int gr = bm + wm + i * 16 + fb * 4 + r;
        float v = acc[i][j][r] + bv;
        if (ACT == 1) v = 0.5f * v * (1.0f + erff(v * 0.70710678118654752f));
        if (RES)      v += R[(size_t)gr * N + gc];
        C[(size_t)gr * N + gc] = v;
      }
    }
  }
}

// ---------------------------------------------------------------- attention (f32, flash-style)
// block = (q-tile of 64 rows, b*h). LDS: Qs, KVs (K then V^T), Ps; all
// [64][64] f32 with XOR swizzle key = ((row>>2)&7)<<4 (conflict-free b128).
#define ASWZ(row, cbyte) ((((row) << 8) + (cbyte)) ^ ((((row) >> 2) & 7) << 4))

__global__ __launch_bounds__(256) void attn_kernel(
    const float* __restrict__ q, const float* __restrict__ k,
    const float* __restrict__ v, float* __restrict__ x)
{
  __shared__ __align__(16) char Qs[64 * 64 * 4];
  __shared__ __align__(16) char KVs[64 * 64 * 4];
  __shared__ __align__(16) char Ps[64 * 64 * 4];

  int tid = threadIdx.x;
  int qt = blockIdx.x, bh = blockIdx.y;
  int b = bh >> 4, h = bh & 15;
  size_t headoff = (size_t)b * T_ * E_ + h * HS_;

  int sr = tid >> 4;   // 0..15
  int sc = tid & 15;   // 0..15

  // stage Q (scale folded in)
#pragma unroll
  for (int p = 0; p < 4; ++p) {
    int r = p * 16 + sr;
    f32x4 qv = *(const f32x4*)(q + headoff + (size_t)(qt * 64 + r) * E_ + sc * 4);
    qv *= SCALE_;
    *(f32x4*)(Qs + ASWZ(r, sc * 16)) = qv;
  }

  int r0 = sr * 4, c0 = sc * 4;
  float m[4], l[4];
  f32x4 O[4];
#pragma unroll
  for (int i = 0; i < 4; ++i) { m[i] = -1e30f; l[i] = 0.f; O[i] = (f32x4){0.f, 0.f, 0.f, 0.f}; }

  int nkt = qt + 1;
  for (int kt = 0; kt < nkt; ++kt) {
    __syncthreads();
    // stage K rows
#pragma unroll
    for (int p = 0; p < 4; ++p) {
      int r = p * 16 + sr;
      f32x4 kv = *(const f32x4*)(k + headoff + (size_t)(kt * 64 + r) * E_ + sc * 4);
      *(f32x4*)(KVs + ASWZ(r, sc * 16)) = kv;
    }
    __syncthreads();

    // S = Q K^T (each thread 4x4)
    float s[4][4];
#pragma unroll
    for (int i = 0; i < 4; ++i)
#pragma unroll
      for (int j = 0; j < 4; ++j) s[i][j] = 0.f;
#pragma unroll
    for (int d4 = 0; d4 < 16; ++d4) {
      f32x4 qv[4], kv[4];
#pragma unroll
      for (int i = 0; i < 4; ++i) qv[i] = *(const f32x4*)(Qs + ASWZ(r0 + i, d4 * 16));
#pragma unroll
      for (int j = 0; j < 4; ++j) kv[j] = *(const f32x4*)(KVs + ASWZ(c0 + j, d4 * 16));
#pragma unroll
      for (int i = 0; i < 4; ++i)
#pragma unroll
        for (int j = 0; j < 4; ++j)
          s[i][j] += qv[i][0]*kv[j][0] + qv[i][1]*kv[j][1] + qv[i][2]*kv[j][2] + qv[i][3]*kv[j][3];
    }

    if (kt == qt) {   // causal mask on the diagonal tile
#pragma unroll
      for (int i = 0; i < 4; ++i)
#pragma unroll
        for (int j = 0; j < 4; ++j)
          if (c0 + j > r0 + i) s[i][j] = -1e30f;
    }

    // online softmax (row stats across the 16 col-threads)
#pragma unroll
    for (int i = 0; i < 4; ++i) {
      float mx = fmaxf(fmaxf(s[i][0], s[i][1]), fmaxf(s[i][2], s[i][3]));
      mx = fmaxf(mx, __shfl_xor(mx, 1, 16));
      mx = fmaxf(mx, __shfl_xor(mx, 2, 16));
      mx = fmaxf(mx, __shfl_xor(mx, 4, 16));
      mx = fmaxf(mx, __shfl_xor(mx, 8, 16));
      float mnew = fmaxf(m[i], mx);
      float p0 = __expf(s[i][0] - mnew);
      float p1 = __expf(s[i][1] - mnew);
      float p2 = __expf(s[i][2] - mnew);
      float p3 = __expf(s[i][3] - mnew);
      float rsum = p0 + p1 + p2 + p3;
      rsum += __shfl_xor(rsum, 1, 16);
      rsum += __shfl_xor(rsum, 2, 16);
      rsum += __shfl_xor(rsum, 4, 16);
      rsum += __shfl_xor(rsum, 8, 16);
      float scl = __expf(m[i] - mnew);
      l[i] = l[i] * scl + rsum;
      m[i] = mnew;
      O[i] *= scl;
      f32x4 pv = {p0, p1, p2, p3};
      *(f32x4*)(Ps + ASWZ(r0 + i, c0 * 4)) = pv;
    }
    __syncthreads();

    // stage V transposed: Vt[d][j] = V[j][d]
#pragma unroll
    for (int p = 0; p < 4; ++p) {
      int j = p * 16 + sr;
      f32x4 vv = *(const f32x4*)(v + headoff + (size_t)(kt * 64 + j) * E_ + sc * 4);
#pragma unroll
      for (int e = 0; e < 4; ++e)
        *(float*)(KVs + ASWZ(sc * 4 + e, j * 4)) = vv[e];
    }
    __syncthreads();

    // O += P V  (O[i] covers d = c0..c0+3)
#pragma unroll
    for (int j4 = 0; j4 < 16; ++j4) {
      f32x4 pr[4], vr[4];
#pragma unroll
      for (int i = 0; i < 4; ++i) pr[i] = *(const f32x4*)(Ps + ASWZ(r0 + i, j4 * 16));
#pragma unroll
      for (int e = 0; e < 4; ++e) vr[e] = *(const f32x4*)(KVs + ASWZ(c0 + e, j4 * 16));
#pragma unroll
      for (int i = 0; i < 4; ++i)
#pragma unroll
        for (int e = 0; e < 4; ++e)
          O[i][e] += pr[i][0]*vr[e][0] + pr[i][1]*vr[e][1] + pr[i][2]*vr[e][2] + pr[i][3]*vr[e][3];
    }
  }

  // x += O / l  (residual add, disjoint per thread)
#pragma unroll
  for (int i = 0; i < 4; ++i) {
    float inv = 1.0f / l[i];
    float* xp = x + headoff + (size_t)(qt * 64 + r0 + i) * E_ + c0;
    f32x4 xv = *(f32x4*)xp;
    xv += O[i] * inv;
    *(f32x4*)xp = xv;
  }
}

// ---------------------------------------------------------------- launch
extern "C" void kernel_launch(void* const* d_in, const int* in_sizes, int n_in,
                              void* d_out, int out_size, void* d_ws, size_t ws_size,
                              hipStream_t stream)
{
  const int*   ids  = (const int*)  d_in[0];
  const float* emb  = (const float*)d_in[1];
  const float* pos  = (const float*)d_in[2];
  const float* wq   = (const float*)d_in[3];
  const float* bq   = (const float*)d_in[4];
  const float* wk   = (const float*)d_in[5];
  const float* bk   = (const float*)d_in[6];
  const float* wv   = (const float*)d_in[7];
  const float* bv   = (const float*)d_in[8];
  const float* w1   = (const float*)d_in[9];
  const float* b1   = (const float*)d_in[10];
  const float* w2   = (const float*)d_in[11];
  const float* b2   = (const float*)d_in[12];
  const float* ln1g = (const float*)d_in[13];
  const float* ln1b = (const float*)d_in[14];
  const float* ln2g = (const float*)d_in[15];
  const float* ln2b = (const float*)d_in[16];
  const float* pw   = (const float*)d_in[17];
  const float* pb   = (const float*)d_in[18];
  float* out = (float*)d_out;

  if (ws_size < (size_t)18 * 1024 * 1024 * sizeof(float)) return;  // need 72 MB

  float* ws = (float*)d_ws;
  float* x  = ws;
  float* h  = ws + (size_t)2 * 1024 * 1024;
  float* qb = ws + (size_t)4 * 1024 * 1024;
  float* kb = ws + (size_t)6 * 1024 * 1024;
  float* vb = ws + (size_t)8 * 1024 * 1024;
  float* ff = ws + (size_t)10 * 1024 * 1024;

  embed_kernel<<<BT_, 256, 0, stream>>>(ids, emb, pos, x);

  for (int l = 0; l < L_; ++l) {
    ln_kernel<<<BT_, 256, 0, stream>>>(x, ln1g + l * E_, ln1b + l * E_, h);

    gemm_kernel<0, 0><<<dim3(E_ / 128, BT_ / 128, 3), 256, 0, stream>>>(
        h,
        wq + (size_t)l * E_ * E_, wk + (size_t)l * E_ * E_, wv + (size_t)l * E_ * E_,
        bq + l * E_, bk + l * E_, bv + l * E_,
        qb, kb, vb,
        nullptr, nullptr, nullptr, BT_, E_, E_);

    attn_kernel<<<dim3(T_ / 64, B_ * H_), 256, 0, stream>>>(qb, kb, vb, x);

    ln_kernel<<<BT_, 256, 0, stream>>>(x, ln2g + l * E_, ln2b + l * E_, h);

    gemm_kernel<1, 0><<<dim3(FF_ / 128, BT_ / 128, 1), 256, 0, stream>>>(
        h, w1 + (size_t)l * E_ * FF_, nullptr, nullptr,
        b1 + l * FF_, nullptr, nullptr,
        ff, nullptr, nullptr,
        nullptr, nullptr, nullptr, BT_, FF_, E_);

    gemm_kernel<0, 1><<<dim3(E_ / 128, BT_ / 128, 1), 256, 0, stream>>>(
        ff, w2 + (size_t)l * FF_ * E_, nullptr, nullptr,
        b2 + l * E_, nullptr, nullptr,
        x, nullptr, nullptr,
        x, nullptr, nullptr, BT_, E_, FF_);
  }

  gemm_kernel<0, 0><<<dim3(V_ / 128, BT_ / 128, 1), 256, 0, stream>>>(
      x, pw, nullptr, nullptr,
      pb, nullptr, nullptr,
      out, nullptr, nullptr,
      nullptr, nullptr, nullptr, BT_, V_, E_);
}

// Round 3
// 954.695 us; speedup vs baseline: 2.4938x; 2.4938x over previous
//
#include <hip/hip_runtime.h>
#include <hip/hip_bf16.h>
#include <cstdint>

#define B_    2
#define T_    1024
#define E_    1024
#define H_    16
#define HS_   64
#define L_    4
#define V_    32000
#define FF_   4096
#define BT_   2048
#define EPS_  1e-5f
#define SCALE_ 0.03125f   // 1/sqrt(E) = 1/32

typedef __bf16 bf16;
typedef bf16  bf16x4 __attribute__((ext_vector_type(4)));
typedef bf16  bf16x8 __attribute__((ext_vector_type(8)));
typedef float f32x4  __attribute__((ext_vector_type(4)));

#define GL2LDS(gp, lp) __builtin_amdgcn_global_load_lds( \
    (const __attribute__((address_space(1))) void*)(gp), \
    (__attribute__((address_space(3))) void*)(lp), 16, 0, 0)

// ---------------------------------------------------------------- embed
__global__ __launch_bounds__(256) void embed_kernel(
    const int* __restrict__ ids, const float* __restrict__ emb,
    const float* __restrict__ pos, float* __restrict__ x)
{
  int bt = blockIdx.x;
  int t  = bt & (T_ - 1);
  int id = ids[bt];
  f32x4 e = *(const f32x4*)(emb + (size_t)id * E_ + threadIdx.x * 4);
  f32x4 p = *(const f32x4*)(pos + (size_t)t  * E_ + threadIdx.x * 4);
  *(f32x4*)(x + (size_t)bt * E_ + threadIdx.x * 4) = e + p;
}

// ---------------------------------------------------------------- layernorm (f32 in, bf16 out)
__device__ __forceinline__ float wred_sum(float v) {
#pragma unroll
  for (int o = 32; o; o >>= 1) v += __shfl_xor(v, o, 64);
  return v;
}

__global__ __launch_bounds__(256) void ln_kernel(
    const float* __restrict__ x, const float* __restrict__ g,
    const float* __restrict__ b, bf16* __restrict__ h)
{
  int row = blockIdx.x, tid = threadIdx.x;
  f32x4 v = *(const f32x4*)(x + (size_t)row * E_ + tid * 4);
  float s  = v[0] + v[1] + v[2] + v[3];
  float sq = v[0]*v[0] + v[1]*v[1] + v[2]*v[2] + v[3]*v[3];
  s  = wred_sum(s);
  sq = wred_sum(sq);
  __shared__ float rs[4], rq[4];
  int w = tid >> 6, lane = tid & 63;
  if (lane == 0) { rs[w] = s; rq[w] = sq; }
  __syncthreads();
  float S = rs[0] + rs[1] + rs[2] + rs[3];
  float Q = rq[0] + rq[1] + rq[2] + rq[3];
  float mean = S * (1.0f / E_);
  float var  = Q * (1.0f / E_) - mean * mean;
  float rstd = rsqrtf(fmaxf(var, 0.0f) + EPS_);
  f32x4 gv = *(const f32x4*)(g + tid * 4);
  f32x4 bv = *(const f32x4*)(b + tid * 4);
  f32x4 o = (v - mean) * rstd * gv + bv;
  bf16x4 ob = { (bf16)o[0], (bf16)o[1], (bf16)o[2], (bf16)o[3] };
  *(bf16x4*)(h + (size_t)row * E_ + tid * 4) = ob;
}

// ---------------------------------------------------------------- weight transpose+convert
// W [K][N] f32 (row stride ldW) -> O [N][K] bf16
__global__ __launch_bounds__(256) void convw_kernel(
    const float* __restrict__ W0, const float* __restrict__ W1, const float* __restrict__ W2,
    bf16* __restrict__ O0, bf16* __restrict__ O1, bf16* __restrict__ O2,
    int K, int ldW)
{
  int z = blockIdx.z;
  const float* W = (z == 0) ? W0 : (z == 1) ? W1 : W2;
  bf16*        O = (z == 0) ? O0 : (z == 1) ? O1 : O2;
  __shared__ float tl[32][33];
  int n0 = blockIdx.x * 32, k0 = blockIdx.y * 32;
  int c = threadIdx.x & 31, r = threadIdx.x >> 5;
#pragma unroll
  for (int p = 0; p < 4; ++p)
    tl[r + p * 8][c] = W[(size_t)(k0 + r + p * 8) * ldW + n0 + c];
  __syncthreads();
#pragma unroll
  for (int p = 0; p < 4; ++p)
    O[(size_t)(n0 + r + p * 8) * K + k0 + c] = (bf16)tl[c][r + p * 8];
}

// ---------------------------------------------------------------- GEMM bf16 MFMA (m97-style)
// A [M][K] bf16, B [N][K] bf16 (pre-transposed). 128x128 tile, BK=32.
// global_load_lds staging, linear LDS dest, XOR-pre-swizzled global source
// (key=(row>>1)&3 on 16B chunks) => 2-way-max conflicts on ds_read_b128.
// Double-buffered LDS, one barrier per K-step.
// MODE: 0 = f32 out (+bias) ; 1 = bf16 out (+bias, ACT opt) ; 2 = f32 out = acc+bias+R and bf16 copy
template <int ACT, int MODE>
__global__ __launch_bounds__(256) void gemm_bf16(
    const bf16* __restrict__ A,
    const bf16* __restrict__ B0, const bf16* __restrict__ B1, const bf16* __restrict__ B2,
    const float* __restrict__ bi0, const float* __restrict__ bi1, const float* __restrict__ bi2,
    bf16* __restrict__ Cb0, bf16* __restrict__ Cb1, bf16* __restrict__ Cb2,
    float* __restrict__ Cf, const float* __restrict__ R,
    int K, int ldc)
{
  int z = blockIdx.z;
  const bf16*  Bm = (z == 0) ? B0 : (z == 1) ? B1 : B2;
  const float* bi = (z == 0) ? bi0 : (z == 1) ? bi1 : bi2;
  bf16*        Cb = (z == 0) ? Cb0 : (z == 1) ? Cb1 : Cb2;

  // panel-local XCD swizzle: 16 M-blocks sharing a B-panel -> same lin%8
  int nb  = (int)(gridDim.x * gridDim.y);      // multiple of 8
  int lin = blockIdx.x + gridDim.x * blockIdx.y;
  int per = nb >> 3;
  int b   = (lin & 7) * per + (lin >> 3);
  int mi  = b & 15;            // gridDim.x == 16 always
  int ni  = b >> 4;

  __shared__ __align__(16) char lds[2][16384];  // [buf][A 8KB | B 8KB]

  int tid = threadIdx.x;
  int lane = tid & 63, wid = tid >> 6;
  int wm = (wid >> 1) * 64, wn = (wid & 1) * 64;
  int fr = lane & 15, fb = lane >> 4;

  const bf16* Asrc = A  + (size_t)(mi * 128) * K;
  const bf16* Bsrc = Bm + (size_t)(ni * 128) * K;

  int NT = K >> 5;

  // staging: issue 'is' covers rows is*64 + tid/4, chunk (tid&3)^key
#define STAGE(buf, kk)                                                          \
  {                                                                             \
    _Pragma("unroll")                                                           \
    for (int is = 0; is < 2; ++is) {                                            \
      int rl = is * 64 + (tid >> 2);                                            \
      int key = (rl >> 1) & 3;                                                  \
      int ck  = ((tid & 3) ^ key) * 8;                                          \
      GL2LDS(Asrc + (size_t)rl * K + (kk) + ck,                                 \
             lds[buf] + is * 4096 + tid * 16);                                  \
      GL2LDS(Bsrc + (size_t)rl * K + (kk) + ck,                                 \
             lds[buf] + 8192 + is * 4096 + tid * 16);                           \
    }                                                                           \
  }

  f32x4 acc[4][4];
#pragma unroll
  for (int i = 0; i < 4; ++i)
#pragma unroll
    for (int j = 0; j < 4; ++j) acc[i][j] = (f32x4){0.f, 0.f, 0.f, 0.f};

  STAGE(0, 0);
  int cur = 0;

  for (int t = 0; t < NT; ++t) {
    __syncthreads();                       // drains vmcnt -> buf[cur] ready
    if (t + 1 < NT) STAGE(cur ^ 1, (t + 1) << 5);

    const char* Ab = lds[cur];
    const char* Bb = lds[cur] + 8192;
    bf16x8 af[4], bfr[4];
#pragma unroll
    for (int i = 0; i < 4; ++i) {
      int rl = wm + i * 16 + fr;
      af[i] = *(const bf16x8*)(Ab + rl * 64 + ((fb ^ ((rl >> 1) & 3)) * 16));
    }
#pragma unroll
    for (int j = 0; j < 4; ++j) {
      int rl = wn + j * 16 + fr;
      bfr[j] = *(const bf16x8*)(Bb + rl * 64 + ((fb ^ ((rl >> 1) & 3)) * 16));
    }
#pragma unroll
    for (int i = 0; i < 4; ++i)
#pragma unroll
      for (int j = 0; j < 4; ++j)
        acc[i][j] = __builtin_amdgcn_mfma_f32_16x16x32_bf16(af[i], bfr[j], acc[i][j], 0, 0, 0);
    cur ^= 1;
  }
#undef STAGE

  // epilogue: C/D layout col = lane&15, row = (lane>>4)*4 + reg
#pragma unroll
  for (int i = 0; i < 4; ++i) {
#pragma unroll
    for (int j = 0; j < 4; ++j) {
      int gc = ni * 128 + wn + j * 16 + fr;
      float bv = bi[gc];
#pragma unroll
      for (int r = 0; r < 4; ++r) {
        int gr = mi * 128 + wm + i * 16 + fb * 4 + r;
        float vv = acc[i][j][r] + bv;
        if (ACT == 1) vv = 0.5f * vv * (1.0f + erff(vv * 0.70710678118654752f));
        if (MODE == 2) {
          float nv = vv + R[(size_t)gr * ldc + gc];
          Cf[(size_t)gr * ldc + gc] = nv;
          Cb[(size_t)gr * ldc + gc] = (bf16)nv;
        } else if (MODE == 1) {
          Cb[(size_t)gr * ldc + gc] = (bf16)vv;
        } else {
          Cf[(size_t)gr * ldc + gc] = vv;
        }
      }
    }
  }
}

// ---------------------------------------------------------------- attention (bf16 MFMA flash)
// block = 256 thr (4 waves), q-tile 64 rows (16/wave), KV-tile 64.
// Q hoisted to A-frags. K staged via global_load_lds (pre-swizzled source),
// V^T reg-staged with bank swizzle, P through per-wave swizzled LDS.
__global__ __launch_bounds__(256) void attn_kernel(
    const bf16* __restrict__ q, const bf16* __restrict__ k,
    const bf16* __restrict__ v, float* __restrict__ x)
{
  __shared__ __align__(16) char Ks[8192];   // [64 c][128B], chunk ^ keyK(c)
  __shared__ __align__(16) char Vs[8192];   // [64 d][128B] (V^T), ^ keyV(d)<<4
  __shared__ __align__(16) char Ps[8192];   // 4 waves x [16 q][128B], ^ key2(row)

  int tid = threadIdx.x, lane = tid & 63, w = tid >> 6;
  int qt = blockIdx.x, bh = blockIdx.y;
  int b = bh >> 4, h = bh & 15;
  size_t hoff = (size_t)b * T_ * E_ + h * HS_;
  int fr = lane & 15, fb = lane >> 4;

  // Q A-frags: lane holds Q[row=fr][d = kc*32 + fb*8 .. +7]
  bf16x8 qa[2];
  {
    const bf16* qp = q + hoff + (size_t)(qt * 64 + w * 16 + fr) * E_ + fb * 8;
    qa[0] = *(const bf16x8*)qp;
    qa[1] = *(const bf16x8*)(qp + 32);
  }

  f32x4 O[4];
  float m_[4], l_[4];
#pragma unroll
  for (int i = 0; i < 4; ++i) { O[i] = (f32x4){0.f,0.f,0.f,0.f}; m_[i] = -1e30f; l_[i] = 0.f; }

  for (int kt = 0; kt <= qt; ++kt) {
    __syncthreads();   // prev tile's readers done
    // --- stage K rows (64 x 64 bf16) via global_load_lds
    {
      const bf16* kbase = k + hoff + (size_t)(kt * 64) * E_;
#pragma unroll
      for (int is = 0; is < 2; ++is) {
        int c = is * 32 + (tid >> 3);
        int key = ((c & 7) ^ (c >> 3)) & 7;
        GL2LDS(kbase + (size_t)c * E_ + (((tid & 7) ^ key) * 8),
               Ks + is * 4096 + tid * 16);
      }
    }
    // --- stage V^T (reg, swizzled scalar writes)
#pragma unroll
    for (int p = 0; p < 2; ++p) {
      int row = tid >> 2;
      int d0 = (tid & 3) * 8 + p * 32;
      bf16x8 vv = *(const bf16x8*)(v + hoff + (size_t)(kt * 64 + row) * E_ + d0);
#pragma unroll
      for (int e = 0; e < 8; ++e) {
        int d = d0 + e;
        int key = ((d & 7) ^ (d >> 3)) & 7;
        *(bf16*)(Vs + d * 128 + ((row * 2) ^ (key << 4))) = vv[e];
      }
    }
    __syncthreads();

    // --- S = Q K^T  (wave's 16 q-rows x 64 k-cols)
    f32x4 s[4];
#pragma unroll
    for (int jc = 0; jc < 4; ++jc) {
      s[jc] = (f32x4){0.f, 0.f, 0.f, 0.f};
#pragma unroll
      for (int kc = 0; kc < 2; ++kc) {
        int c = jc * 16 + fr;
        int key = ((c & 7) ^ (c >> 3)) & 7;
        bf16x8 kf = *(const bf16x8*)(Ks + c * 128 + ((kc * 64 + fb * 16) ^ (key << 4)));
        s[jc] = __builtin_amdgcn_mfma_f32_16x16x32_bf16(qa[kc], kf, s[jc], 0, 0, 0);
      }
    }

    // --- online softmax, P write (per-wave LDS region)
    char* pbase = Ps + w * 2048;
#pragma unroll
    for (int r = 0; r < 4; ++r) {
      float s0 = s[0][r] * SCALE_, s1 = s[1][r] * SCALE_;
      float s2 = s[2][r] * SCALE_, s3 = s[3][r] * SCALE_;
      int qrow = qt * 64 + w * 16 + fb * 4 + r;
      if (kt == qt) {
        int kc0 = kt * 64 + fr;
        if (kc0      > qrow) s0 = -1e30f;
        if (kc0 + 16 > qrow) s1 = -1e30f;
        if (kc0 + 32 > qrow) s2 = -1e30f;
        if (kc0 + 48 > qrow) s3 = -1e30f;
      }
      float mx = fmaxf(fmaxf(s0, s1), fmaxf(s2, s3));
      mx = fmaxf(mx, __shfl_xor(mx, 1, 16));
      mx = fmaxf(mx, __shfl_xor(mx, 2, 16));
      mx = fmaxf(mx, __shfl_xor(mx, 4, 16));
      mx = fmaxf(mx, __shfl_xor(mx, 8, 16));
      float mnew = fmaxf(m_[r], mx);
      float p0 = __expf(s0 - mnew), p1 = __expf(s1 - mnew);
      float p2 = __expf(s2 - mnew), p3 = __expf(s3 - mnew);
      float rs = p0 + p1 + p2 + p3;
      rs += __shfl_xor(rs, 1, 16);
      rs += __shfl_xor(rs, 2, 16);
      rs += __shfl_xor(rs, 4, 16);
      rs += __shfl_xor(rs, 8, 16);
      float scl = __expf(m_[r] - mnew);
      l_[r] = l_[r] * scl + rs;
      m_[r] = mnew;
#pragma unroll
      for (int jd = 0; jd < 4; ++jd) O[jd][r] *= scl;
      // P row = fb*4 + r ; key2 = (r<<4)^(fb<<5)
      int key2 = (r << 4) ^ (fb << 5);
      char* pr_ = pbase + (fb * 4 + r) * 128;
      *(bf16*)(pr_ + (( 0 + fr * 2) ^ key2)) = (bf16)p0;
      *(bf16*)(pr_ + ((32 + fr * 2) ^ key2)) = (bf16)p1;
      *(bf16*)(pr_ + ((64 + fr * 2) ^ key2)) = (bf16)p2;
      *(bf16*)(pr_ + ((96 + fr * 2) ^ key2)) = (bf16)p3;
    }

    // --- O += P V   (A = P frags, B = V^T rows)
#pragma unroll
    for (int kc = 0; kc < 2; ++kc) {
      int key2 = ((fr & 3) << 4) ^ ((fr >> 2) << 5);
      bf16x8 pa = *(const bf16x8*)(pbase + fr * 128 + ((kc * 64 + fb * 16) ^ key2));
#pragma unroll
      for (int jd = 0; jd < 4; ++jd) {
        int d = jd * 16 + fr;
        int key = ((d & 7) ^ (d >> 3)) & 7;
        bf16x8 vf = *(const bf16x8*)(Vs + d * 128 + ((kc * 64 + fb * 16) ^ (key << 4)));
        O[jd] = __builtin_amdgcn_mfma_f32_16x16x32_bf16(pa, vf, O[jd], 0, 0, 0);
      }
    }
  }

  // --- x += O / l
#pragma unroll
  for (int r = 0; r < 4; ++r) {
    float inv = 1.0f / l_[r];
    float* xp = x + hoff + (size_t)(qt * 64 + w * 16 + fb * 4 + r) * E_;
#pragma unroll
    for (int jd = 0; jd < 4; ++jd) {
      int d = jd * 16 + fr;
      xp[d] += O[jd][r] * inv;
    }
  }
}

// ---------------------------------------------------------------- launch
extern "C" void kernel_launch(void* const* d_in, const int* in_sizes, int n_in,
                              void* d_out, int out_size, void* d_ws, size_t ws_size,
                              hipStream_t stream)
{
  const int*   ids  = (const int*)  d_in[0];
  const float* emb  = (const float*)d_in[1];
  const float* pos  = (const float*)d_in[2];
  const float* wq   = (const float*)d_in[3];
  const float* bq   = (const float*)d_in[4];
  const float* wk   = (const float*)d_in[5];
  const float* bk   = (const float*)d_in[6];
  const float* wv   = (const float*)d_in[7];
  const float* bv   = (const float*)d_in[8];
  const float* w1   = (const float*)d_in[9];
  const float* b1   = (const float*)d_in[10];
  const float* w2   = (const float*)d_in[11];
  const float* b2   = (const float*)d_in[12];
  const float* ln1g = (const float*)d_in[13];
  const float* ln1b = (const float*)d_in[14];
  const float* ln2g = (const float*)d_in[15];
  const float* ln2b = (const float*)d_in[16];
  const float* pw   = (const float*)d_in[17];
  const float* pb   = (const float*)d_in[18];
  float* out = (float*)d_out;

  // ws layout (f32 units), NON-overlapping (round-2 bug was aliasing here):
  //   x   [ 0M,  2M)  f32  BTxE
  //   xb  [ 2M,  3M)  bf16 BTxE
  //   hb  [ 3M,  4M)  bf16 BTxE
  //   qb  [ 4M,  5M)  bf16 BTxE
  //   kb  [ 5M,  6M)  bf16 BTxE
  //   vb  [ 6M,  7M)  bf16 BTxE
  //   ffb [ 7M, 11M)  bf16 BTxFF
  //   lwb [11M, 16.5M) bf16 layer weights (wq,wk,wv 1M bf16 each; w1 4M; w2 4M)
  //   pwb [ 3M, 11.2M) bf16 proj-weight chunk (reuses hb..ffb + 0.2M of lwb,
  //                    all dead at projection time)
  // peak = 16.5M f32 = 66 MiB  (round 1 proved ws_size >= 72 MB)
  if (ws_size < (size_t)66 * 1024 * 1024) return;
  float* ws = (float*)d_ws;
  float* x   = ws;
  bf16*  xb  = (bf16*)(ws + (size_t) 2 * 1024 * 1024);
  bf16*  hb  = (bf16*)(ws + (size_t) 3 * 1024 * 1024);
  bf16*  qb  = (bf16*)(ws + (size_t) 4 * 1024 * 1024);
  bf16*  kb  = (bf16*)(ws + (size_t) 5 * 1024 * 1024);
  bf16*  vb  = (bf16*)(ws + (size_t) 6 * 1024 * 1024);
  bf16*  ffb = (bf16*)(ws + (size_t) 7 * 1024 * 1024);
  bf16*  lwb = (bf16*)(ws + (size_t)11 * 1024 * 1024);
  bf16*  pwb = (bf16*)(ws + (size_t) 3 * 1024 * 1024);
  bf16*  wqt = lwb;                                  // 1M bf16
  bf16*  wkt = lwb + (size_t)1 * 1024 * 1024;        // 1M bf16
  bf16*  wvt = lwb + (size_t)2 * 1024 * 1024;        // 1M bf16
  bf16*  w1t = lwb + (size_t)3 * 1024 * 1024;        // 4M bf16
  bf16*  w2t = lwb + (size_t)7 * 1024 * 1024;        // 4M bf16

  embed_kernel<<<BT_, 256, 0, stream>>>(ids, emb, pos, x);

  for (int l = 0; l < L_; ++l) {
    const size_t lEE = (size_t)l * E_ * E_;
    const size_t lEF = (size_t)l * E_ * FF_;

    // weight conversions for this layer
    convw_kernel<<<dim3(E_/32, E_/32, 3), 256, 0, stream>>>(
        wq + lEE, wk + lEE, wv + lEE, wqt, wkt, wvt, E_, E_);
    convw_kernel<<<dim3(FF_/32, E_/32, 1), 256, 0, stream>>>(
        w1 + lEF, nullptr, nullptr, w1t, nullptr, nullptr, E_, FF_);
    convw_kernel<<<dim3(E_/32, FF_/32, 1), 256, 0, stream>>>(
        w2 + lEF, nullptr, nullptr, w2t, nullptr, nullptr, FF_, E_);

    ln_kernel<<<BT_, 256, 0, stream>>>(x, ln1g + l*E_, ln1b + l*E_, hb);

    gemm_bf16<0,1><<<dim3(16, E_/128, 3), 256, 0, stream>>>(
        hb, wqt, wkt, wvt, bq + l*E_, bk + l*E_, bv + l*E_,
        qb, kb, vb, nullptr, nullptr, E_, E_);

    attn_kernel<<<dim3(T_/64, B_*H_), 256, 0, stream>>>(qb, kb, vb, x);

    ln_kernel<<<BT_, 256, 0, stream>>>(x, ln2g + l*E_, ln2b + l*E_, hb);

    gemm_bf16<1,1><<<dim3(16, FF_/128, 1), 256, 0, stream>>>(
        hb, w1t, nullptr, nullptr, b1 + (size_t)l*FF_, nullptr, nullptr,
        ffb, nullptr, nullptr, nullptr, nullptr, E_, FF_);

    gemm_bf16<0,2><<<dim3(16, E_/128, 1), 256, 0, stream>>>(
        ffb, w2t, nullptr, nullptr, b2 + l*E_, nullptr, nullptr,
        xb, nullptr, nullptr, x, x, FF_, E_);
  }

  // final projection in two 16000-col chunks (converted into pwb)
  for (int cchunk = 0; cchunk < 2; ++cchunk) {
    int c0 = cchunk * 16000;
    convw_kernel<<<dim3(16000/32, E_/32, 1), 256, 0, stream>>>(
        pw + c0, nullptr, nullptr, pwb, nullptr, nullptr, E_, V_);
    gemm_bf16<0,0><<<dim3(16, 16000/128, 1), 256, 0, stream>>>(
        xb, pwb, nullptr, nullptr, pb + c0, nullptr, nullptr,
        nullptr, nullptr, nullptr, out + c0, nullptr, E_, V_);
  }
}

// Round 4
// 860.601 us; speedup vs baseline: 2.7664x; 1.1093x over previous
//
#include <hip/hip_runtime.h>
#include <hip/hip_bf16.h>
#include <cstdint>

#define B_    2
#define T_    1024
#define E_    1024
#define H_    16
#define HS_   64
#define L_    4
#define V_    32000
#define FF_   4096
#define BT_   2048
#define EPS_  1e-5f
#define SCALE_ 0.03125f   // 1/sqrt(E) = 1/32

typedef __bf16 bf16;
typedef bf16  bf16x4 __attribute__((ext_vector_type(4)));
typedef bf16  bf16x8 __attribute__((ext_vector_type(8)));
typedef float f32x4  __attribute__((ext_vector_type(4)));

#define GL2LDS(gp, lp) __builtin_amdgcn_global_load_lds( \
    (const __attribute__((address_space(1))) void*)(gp), \
    (__attribute__((address_space(3))) void*)(lp), 16, 0, 0)

// ---------------------------------------------------------------- embed
__global__ __launch_bounds__(256) void embed_kernel(
    const int* __restrict__ ids, const float* __restrict__ emb,
    const float* __restrict__ pos, float* __restrict__ x)
{
  int bt = blockIdx.x;
  int t  = bt & (T_ - 1);
  int id = ids[bt];
  f32x4 e = *(const f32x4*)(emb + (size_t)id * E_ + threadIdx.x * 4);
  f32x4 p = *(const f32x4*)(pos + (size_t)t  * E_ + threadIdx.x * 4);
  *(f32x4*)(x + (size_t)bt * E_ + threadIdx.x * 4) = e + p;
}

// ---------------------------------------------------------------- layernorm (f32 in, bf16 out)
__device__ __forceinline__ float wred_sum(float v) {
#pragma unroll
  for (int o = 32; o; o >>= 1) v += __shfl_xor(v, o, 64);
  return v;
}

__global__ __launch_bounds__(256) void ln_kernel(
    const float* __restrict__ x, const float* __restrict__ g,
    const float* __restrict__ b, bf16* __restrict__ h)
{
  int row = blockIdx.x, tid = threadIdx.x;
  f32x4 v = *(const f32x4*)(x + (size_t)row * E_ + tid * 4);
  float s  = v[0] + v[1] + v[2] + v[3];
  float sq = v[0]*v[0] + v[1]*v[1] + v[2]*v[2] + v[3]*v[3];
  s  = wred_sum(s);
  sq = wred_sum(sq);
  __shared__ float rs[4], rq[4];
  int w = tid >> 6, lane = tid & 63;
  if (lane == 0) { rs[w] = s; rq[w] = sq; }
  __syncthreads();
  float S = rs[0] + rs[1] + rs[2] + rs[3];
  float Q = rq[0] + rq[1] + rq[2] + rq[3];
  float mean = S * (1.0f / E_);
  float var  = Q * (1.0f / E_) - mean * mean;
  float rstd = rsqrtf(fmaxf(var, 0.0f) + EPS_);
  f32x4 gv = *(const f32x4*)(g + tid * 4);
  f32x4 bv = *(const f32x4*)(b + tid * 4);
  f32x4 o = (v - mean) * rstd * gv + bv;
  bf16x4 ob = { (bf16)o[0], (bf16)o[1], (bf16)o[2], (bf16)o[3] };
  *(bf16x4*)(h + (size_t)row * E_ + tid * 4) = ob;
}

// ---------------------------------------------------------------- weight transpose+convert
// W [K][N] f32 (row stride ldW) -> O [N][K] bf16
__global__ __launch_bounds__(256) void convw_kernel(
    const float* __restrict__ W0, const float* __restrict__ W1, const float* __restrict__ W2,
    bf16* __restrict__ O0, bf16* __restrict__ O1, bf16* __restrict__ O2,
    int K, int ldW)
{
  int z = blockIdx.z;
  const float* W = (z == 0) ? W0 : (z == 1) ? W1 : W2;
  bf16*        O = (z == 0) ? O0 : (z == 1) ? O1 : O2;
  __shared__ float tl[32][33];
  int n0 = blockIdx.x * 32, k0 = blockIdx.y * 32;
  int c = threadIdx.x & 31, r = threadIdx.x >> 5;
#pragma unroll
  for (int p = 0; p < 4; ++p)
    tl[r + p * 8][c] = W[(size_t)(k0 + r + p * 8) * ldW + n0 + c];
  __syncthreads();
#pragma unroll
  for (int p = 0; p < 4; ++p)
    O[(size_t)(n0 + r + p * 8) * K + k0 + c] = (bf16)tl[c][r + p * 8];
}

// ---------------------------------------------------------------- GEMM bf16 MFMA 128x128 (m97-style)
// A [M][LDK] bf16, B [N][LDK] bf16. BK=32, global_load_lds staging with
// XOR-pre-swizzled global source, double-buffered LDS, barrier/K-step.
// MODE: 1 = bf16 out (+bias, ACT opt) ; 2 = f32 out = acc+bias+R and bf16 copy ;
//       3 = f32 raw partial at Cf + z*BT_*ldc (split-K over blockIdx.z, no bias)
template <int ACT, int MODE>
__global__ __launch_bounds__(256) void gemm_bf16(
    const bf16* __restrict__ A,
    const bf16* __restrict__ B0, const bf16* __restrict__ B1, const bf16* __restrict__ B2,
    const float* __restrict__ bi0, const float* __restrict__ bi1, const float* __restrict__ bi2,
    bf16* __restrict__ Cb0, bf16* __restrict__ Cb1, bf16* __restrict__ Cb2,
    float* __restrict__ Cf, const float* __restrict__ R,
    int K, int ldc, int LDK)
{
  int z = blockIdx.z;
  const bf16*  Bm = (MODE == 3) ? B0 : (z == 0) ? B0 : (z == 1) ? B1 : B2;
  const float* bi = (z == 0) ? bi0 : (z == 1) ? bi1 : bi2;
  bf16*        Cb = (z == 0) ? Cb0 : (z == 1) ? Cb1 : Cb2;
  int koff = (MODE == 3) ? z * K : 0;

  // chunked XCD swizzle: XCD gets a contiguous tile range -> B-panel locality
  int nb  = (int)(gridDim.x * gridDim.y);      // multiple of 8
  int lin = blockIdx.x + gridDim.x * blockIdx.y;
  int per = nb >> 3;
  int b   = (lin & 7) * per + (lin >> 3);
  int mi  = b & 15;            // gridDim.x == 16 always
  int ni  = b >> 4;

  __shared__ __align__(16) char lds[2][16384];  // [buf][A 8KB | B 8KB]

  int tid = threadIdx.x;
  int lane = tid & 63, wid = tid >> 6;
  int wm = (wid >> 1) * 64, wn = (wid & 1) * 64;
  int fr = lane & 15, fb = lane >> 4;

  const bf16* Asrc = A  + (size_t)(mi * 128) * LDK + koff;
  const bf16* Bsrc = Bm + (size_t)(ni * 128) * LDK + koff;

  int NT = K >> 5;

#define STAGE(buf, kk)                                                          \
  {                                                                             \
    _Pragma("unroll")                                                           \
    for (int is = 0; is < 2; ++is) {                                            \
      int rl = is * 64 + (tid >> 2);                                            \
      int key = (rl >> 1) & 3;                                                  \
      int ck  = ((tid & 3) ^ key) * 8;                                          \
      GL2LDS(Asrc + (size_t)rl * LDK + (kk) + ck,                               \
             lds[buf] + is * 4096 + tid * 16);                                  \
      GL2LDS(Bsrc + (size_t)rl * LDK + (kk) + ck,                               \
             lds[buf] + 8192 + is * 4096 + tid * 16);                           \
    }                                                                           \
  }

  f32x4 acc[4][4];
#pragma unroll
  for (int i = 0; i < 4; ++i)
#pragma unroll
    for (int j = 0; j < 4; ++j) acc[i][j] = (f32x4){0.f, 0.f, 0.f, 0.f};

  STAGE(0, 0);
  int cur = 0;

  for (int t = 0; t < NT; ++t) {
    __syncthreads();                       // drains vmcnt -> buf[cur] ready
    if (t + 1 < NT) STAGE(cur ^ 1, (t + 1) << 5);

    const char* Ab = lds[cur];
    const char* Bb = lds[cur] + 8192;
    bf16x8 af[4], bfr[4];
#pragma unroll
    for (int i = 0; i < 4; ++i) {
      int rl = wm + i * 16 + fr;
      af[i] = *(const bf16x8*)(Ab + rl * 64 + ((fb ^ ((rl >> 1) & 3)) * 16));
    }
#pragma unroll
    for (int j = 0; j < 4; ++j) {
      int rl = wn + j * 16 + fr;
      bfr[j] = *(const bf16x8*)(Bb + rl * 64 + ((fb ^ ((rl >> 1) & 3)) * 16));
    }
#pragma unroll
    for (int i = 0; i < 4; ++i)
#pragma unroll
      for (int j = 0; j < 4; ++j)
        acc[i][j] = __builtin_amdgcn_mfma_f32_16x16x32_bf16(af[i], bfr[j], acc[i][j], 0, 0, 0);
    cur ^= 1;
  }
#undef STAGE

  // epilogue: C/D layout col = lane&15, row = (lane>>4)*4 + reg
#pragma unroll
  for (int i = 0; i < 4; ++i) {
#pragma unroll
    for (int j = 0; j < 4; ++j) {
      int gc = ni * 128 + wn + j * 16 + fr;
      float bv = (MODE == 3) ? 0.f : bi[gc];
#pragma unroll
      for (int r = 0; r < 4; ++r) {
        int gr = mi * 128 + wm + i * 16 + fb * 4 + r;
        float vv = acc[i][j][r] + bv;
        if (ACT == 1) vv = 0.5f * vv * (1.0f + erff(vv * 0.70710678118654752f));
        if (MODE == 2) {
          float nv = vv + R[(size_t)gr * ldc + gc];
          Cf[(size_t)gr * ldc + gc] = nv;
          Cb[(size_t)gr * ldc + gc] = (bf16)nv;
        } else if (MODE == 1) {
          Cb[(size_t)gr * ldc + gc] = (bf16)vv;
        } else if (MODE == 3) {
          Cf[(size_t)(z * BT_ + gr) * ldc + gc] = vv;
        }
      }
    }
  }
}

// ---------------------------------------------------------------- FFN2 split-K combine
// x += p0 + p1 + bias ; xb = bf16(x)
__global__ __launch_bounds__(256) void combine_kernel(
    const float* __restrict__ p, const float* __restrict__ bi,
    float* __restrict__ x, bf16* __restrict__ xb)
{
  int row = blockIdx.x, tid = threadIdx.x;
  size_t off = (size_t)row * E_ + tid * 4;
  f32x4 a = *(const f32x4*)(p + off);
  f32x4 c = *(const f32x4*)(p + (size_t)BT_ * E_ + off);
  f32x4 bv = *(const f32x4*)(bi + tid * 4);
  f32x4 xv = *(const f32x4*)(x + off);
  f32x4 nv = xv + a + c + bv;
  *(f32x4*)(x + off) = nv;
  bf16x4 ob = { (bf16)nv[0], (bf16)nv[1], (bf16)nv[2], (bf16)nv[3] };
  *(bf16x4*)(xb + off) = ob;
}

// ---------------------------------------------------------------- GEMM bf16 MFMA 256x256, BK=64
// 512 thr (8 waves, 2Mx4N), counted-vmcnt deep pipeline (T3/T4-lite), T5 setprio.
// A [M][K], B [N][K] bf16; C f32 [M][N] + bias. Grid: 8*(N/256) blocks, N%256==0.
// LDS 128 KiB: 2 buf x (A 32KB | B 32KB). Swizzle involution: chunk ^= row&7
// (pre-applied on global source, re-applied on ds_read) -> b128 reads at the
// 8-cycle LDS floor.
__global__ __launch_bounds__(512, 2) void gemm256_kernel(
    const bf16* __restrict__ A, const bf16* __restrict__ Bm,
    const float* __restrict__ bi, float* __restrict__ C, int K, int N)
{
  int nwg = (int)gridDim.x;
  int per = nwg >> 3;
  int bid = (int)blockIdx.x;
  int tl  = (bid & 7) * per + (bid >> 3);   // chunked XCD swizzle (nwg%8==0)
  int mi  = tl & 7, ni = tl >> 3;           // mi fastest -> panel locality

  __shared__ __align__(16) char lds[2][65536];

  int tid = threadIdx.x;
  int lane = tid & 63, wid = tid >> 6;
  int wr = wid >> 2, wc = wid & 3;          // 2 x 4 waves
  int fr = lane & 15, fb = lane >> 4;

  const bf16* Asrc = A  + (size_t)(mi * 256) * K;
  const bf16* Bsrc = Bm + (size_t)(ni * 256) * K;

  int NT = K >> 6;

#define STAGE256(buf, kk)                                                  \
  { _Pragma("unroll")                                                      \
    for (int h = 0; h < 2; ++h) {                                          \
      _Pragma("unroll")                                                    \
      for (int is = 0; is < 2; ++is) {                                     \
        int ri  = is * 64 + (tid >> 3);                                    \
        int ck  = (tid & 7) ^ (ri & 7);                                    \
        int row = h * 128 + ri;                                            \
        GL2LDS(Asrc + (size_t)row * K + (kk) + ck * 8,                     \
               lds[buf] + h * 16384 + is * 8192 + tid * 16);               \
        GL2LDS(Bsrc + (size_t)row * K + (kk) + ck * 8,                     \
               lds[buf] + 32768 + h * 16384 + is * 8192 + tid * 16);       \
      }                                                                    \
    } }

  f32x4 acc[8][4];
#pragma unroll
  for (int i = 0; i < 8; ++i)
#pragma unroll
    for (int j = 0; j < 4; ++j) acc[i][j] = (f32x4){0.f, 0.f, 0.f, 0.f};

  STAGE256(0, 0);

  for (int t = 0; t < NT; ++t) {
    int buf = t & 1;
    if (t + 1 < NT) {
      STAGE256(buf ^ 1, (t + 1) << 6);
      asm volatile("s_waitcnt vmcnt(8)" ::: "memory");   // tile t landed; t+1 in flight
    } else {
      asm volatile("s_waitcnt vmcnt(0)" ::: "memory");
    }
    __builtin_amdgcn_s_barrier();
    asm volatile("" ::: "memory");

    const char* Ab = lds[buf];
    const char* Bb = lds[buf] + 32768;

    bf16x8 bfr[4][2];
#pragma unroll
    for (int n2 = 0; n2 < 4; ++n2) {
      int row = wc * 64 + n2 * 16 + fr;
#pragma unroll
      for (int ks = 0; ks < 2; ++ks)
        bfr[n2][ks] = *(const bf16x8*)(Bb + (row >> 7) * 16384 + (row & 127) * 128
                                          + ((((ks * 4 + fb) ^ (fr & 7))) << 4));
    }
#pragma unroll
    for (int q = 0; q < 4; ++q) {
      bf16x8 af[2][2];
#pragma unroll
      for (int m2 = 0; m2 < 2; ++m2) {
        int ri = (q * 2 + m2) * 16 + fr;    // within half wr
#pragma unroll
        for (int ks = 0; ks < 2; ++ks)
          af[m2][ks] = *(const bf16x8*)(Ab + wr * 16384 + ri * 128
                                           + ((((ks * 4 + fb) ^ (fr & 7))) << 4));
      }
      __builtin_amdgcn_s_setprio(1);
#pragma unroll
      for (int m2 = 0; m2 < 2; ++m2)
#pragma unroll
        for (int n2 = 0; n2 < 4; ++n2)
#pragma unroll
          for (int ks = 0; ks < 2; ++ks)
            acc[q * 2 + m2][n2] = __builtin_amdgcn_mfma_f32_16x16x32_bf16(
                af[m2][ks], bfr[n2][ks], acc[q * 2 + m2][n2], 0, 0, 0);
      __builtin_amdgcn_s_setprio(0);
    }
    asm volatile("" ::: "memory");
    __builtin_amdgcn_s_barrier();            // reads done before next stage overwrites
  }
#undef STAGE256

#pragma unroll
  for (int i = 0; i < 8; ++i) {
#pragma unroll
    for (int j = 0; j < 4; ++j) {
      int gc = ni * 256 + wc * 64 + j * 16 + fr;
      float bv = bi[gc];
#pragma unroll
      for (int r = 0; r < 4; ++r) {
        int gr = mi * 256 + wr * 128 + i * 16 + fb * 4 + r;
        C[(size_t)gr * N + gc] = acc[i][j][r] + bv;
      }
    }
  }
}

// ---------------------------------------------------------------- attention (bf16 MFMA flash)
__global__ __launch_bounds__(256) void attn_kernel(
    const bf16* __restrict__ q, const bf16* __restrict__ k,
    const bf16* __restrict__ v, float* __restrict__ x)
{
  __shared__ __align__(16) char Ks[8192];
  __shared__ __align__(16) char Vs[8192];
  __shared__ __align__(16) char Ps[8192];

  int tid = threadIdx.x, lane = tid & 63, w = tid >> 6;
  int qt = blockIdx.x, bh = blockIdx.y;
  int b = bh >> 4, h = bh & 15;
  size_t hoff = (size_t)b * T_ * E_ + h * HS_;
  int fr = lane & 15, fb = lane >> 4;

  bf16x8 qa[2];
  {
    const bf16* qp = q + hoff + (size_t)(qt * 64 + w * 16 + fr) * E_ + fb * 8;
    qa[0] = *(const bf16x8*)qp;
    qa[1] = *(const bf16x8*)(qp + 32);
  }

  f32x4 O[4];
  float m_[4], l_[4];
#pragma unroll
  for (int i = 0; i < 4; ++i) { O[i] = (f32x4){0.f,0.f,0.f,0.f}; m_[i] = -1e30f; l_[i] = 0.f; }

  for (int kt = 0; kt <= qt; ++kt) {
    __syncthreads();
    {
      const bf16* kbase = k + hoff + (size_t)(kt * 64) * E_;
#pragma unroll
      for (int is = 0; is < 2; ++is) {
        int c = is * 32 + (tid >> 3);
        int key = ((c & 7) ^ (c >> 3)) & 7;
        GL2LDS(kbase + (size_t)c * E_ + (((tid & 7) ^ key) * 8),
               Ks + is * 4096 + tid * 16);
      }
    }
#pragma unroll
    for (int p = 0; p < 2; ++p) {
      int row = tid >> 2;
      int d0 = (tid & 3) * 8 + p * 32;
      bf16x8 vv = *(const bf16x8*)(v + hoff + (size_t)(kt * 64 + row) * E_ + d0);
#pragma unroll
      for (int e = 0; e < 8; ++e) {
        int d = d0 + e;
        int key = ((d & 7) ^ (d >> 3)) & 7;
        *(bf16*)(Vs + d * 128 + ((row * 2) ^ (key << 4))) = vv[e];
      }
    }
    __syncthreads();

    f32x4 s[4];
#pragma unroll
    for (int jc = 0; jc < 4; ++jc) {
      s[jc] = (f32x4){0.f, 0.f, 0.f, 0.f};
#pragma unroll
      for (int kc = 0; kc < 2; ++kc) {
        int c = jc * 16 + fr;
        int key = ((c & 7) ^ (c >> 3)) & 7;
        bf16x8 kf = *(const bf16x8*)(Ks + c * 128 + ((kc * 64 + fb * 16) ^ (key << 4)));
        s[jc] = __builtin_amdgcn_mfma_f32_16x16x32_bf16(qa[kc], kf, s[jc], 0, 0, 0);
      }
    }

    char* pbase = Ps + w * 2048;
#pragma unroll
    for (int r = 0; r < 4; ++r) {
      float s0 = s[0][r] * SCALE_, s1 = s[1][r] * SCALE_;
      float s2 = s[2][r] * SCALE_, s3 = s[3][r] * SCALE_;
      int qrow = qt * 64 + w * 16 + fb * 4 + r;
      if (kt == qt) {
        int kc0 = kt * 64 + fr;
        if (kc0      > qrow) s0 = -1e30f;
        if (kc0 + 16 > qrow) s1 = -1e30f;
        if (kc0 + 32 > qrow) s2 = -1e30f;
        if (kc0 + 48 > qrow) s3 = -1e30f;
      }
      float mx = fmaxf(fmaxf(s0, s1), fmaxf(s2, s3));
      mx = fmaxf(mx, __shfl_xor(mx, 1, 16));
      mx = fmaxf(mx, __shfl_xor(mx, 2, 16));
      mx = fmaxf(mx, __shfl_xor(mx, 4, 16));
      mx = fmaxf(mx, __shfl_xor(mx, 8, 16));
      float mnew = fmaxf(m_[r], mx);
      float p0 = __expf(s0 - mnew), p1 = __expf(s1 - mnew);
      float p2 = __expf(s2 - mnew), p3 = __expf(s3 - mnew);
      float rs = p0 + p1 + p2 + p3;
      rs += __shfl_xor(rs, 1, 16);
      rs += __shfl_xor(rs, 2, 16);
      rs += __shfl_xor(rs, 4, 16);
      rs += __shfl_xor(rs, 8, 16);
      float scl = __expf(m_[r] - mnew);
      l_[r] = l_[r] * scl + rs;
      m_[r] = mnew;
#pragma unroll
      for (int jd = 0; jd < 4; ++jd) O[jd][r] *= scl;
      int key2 = (r << 4) ^ (fb << 5);
      char* pr_ = pbase + (fb * 4 + r) * 128;
      *(bf16*)(pr_ + (( 0 + fr * 2) ^ key2)) = (bf16)p0;
      *(bf16*)(pr_ + ((32 + fr * 2) ^ key2)) = (bf16)p1;
      *(bf16*)(pr_ + ((64 + fr * 2) ^ key2)) = (bf16)p2;
      *(bf16*)(pr_ + ((96 + fr * 2) ^ key2)) = (bf16)p3;
    }

#pragma unroll
    for (int kc = 0; kc < 2; ++kc) {
      int key2 = ((fr & 3) << 4) ^ ((fr >> 2) << 5);
      bf16x8 pa = *(const bf16x8*)(pbase + fr * 128 + ((kc * 64 + fb * 16) ^ key2));
#pragma unroll
      for (int jd = 0; jd < 4; ++jd) {
        int d = jd * 16 + fr;
        int key = ((d & 7) ^ (d >> 3)) & 7;
        bf16x8 vf = *(const bf16x8*)(Vs + d * 128 + ((kc * 64 + fb * 16) ^ (key << 4)));
        O[jd] = __builtin_amdgcn_mfma_f32_16x16x32_bf16(pa, vf, O[jd], 0, 0, 0);
      }
    }
  }

#pragma unroll
  for (int r = 0; r < 4; ++r) {
    float inv = 1.0f / l_[r];
    float* xp = x + hoff + (size_t)(qt * 64 + w * 16 + fb * 4 + r) * E_;
#pragma unroll
    for (int jd = 0; jd < 4; ++jd) {
      int d = jd * 16 + fr;
      xp[d] += O[jd][r] * inv;
    }
  }
}

// ---------------------------------------------------------------- launch
extern "C" void kernel_launch(void* const* d_in, const int* in_sizes, int n_in,
                              void* d_out, int out_size, void* d_ws, size_t ws_size,
                              hipStream_t stream)
{
  const int*   ids  = (const int*)  d_in[0];
  const float* emb  = (const float*)d_in[1];
  const float* pos  = (const float*)d_in[2];
  const float* wq   = (const float*)d_in[3];
  const float* bq   = (const float*)d_in[4];
  const float* wk   = (const float*)d_in[5];
  const float* bk   = (const float*)d_in[6];
  const float* wv   = (const float*)d_in[7];
  const float* bv   = (const float*)d_in[8];
  const float* w1   = (const float*)d_in[9];
  const float* b1   = (const float*)d_in[10];
  const float* w2   = (const float*)d_in[11];
  const float* b2   = (const float*)d_in[12];
  const float* ln1g = (const float*)d_in[13];
  const float* ln1b = (const float*)d_in[14];
  const float* ln2g = (const float*)d_in[15];
  const float* ln2b = (const float*)d_in[16];
  const float* pw   = (const float*)d_in[17];
  const float* pb   = (const float*)d_in[18];
  float* out = (float*)d_out;

  // ws layout (f32 units), all regions non-overlapping in time:
  //   x   [ 0M,  2M)  f32  BTxE
  //   hb  [ 2M,  3M)  bf16 BTxE       } fp0 [2M,4M), fp1 [4M,6M) alias these
  //   qb  [ 3M,  4M)  bf16 BTxE       }   (hb/qb/kb/vb dead at FFN2 time)
  //   kb  [ 4M,  5M)  bf16 BTxE
  //   vb  [ 5M,  6M)  bf16 BTxE
  //   ffb [ 6M, 10M)  bf16 BTxFF
  //   lwb [10M,15.5M) bf16 layer weights (qkv 0.5M f32 each, w1/w2 2M f32)
  //   xb  [16M, 17M)  bf16 BTxE
  //   pwb [ 0M, 16M)  bf16 proj weight 32000x1024 (everything below dead then)
  // peak = 17M f32 = 68 MiB (round 1 proved ws >= 72 MiB)
  if (ws_size < (size_t)17 * 1024 * 1024 * 4) return;
  float* ws = (float*)d_ws;
  float* x   = ws;
  bf16*  hb  = (bf16*)(ws + (size_t) 2 * 1024 * 1024);
  bf16*  qb  = (bf16*)(ws + (size_t) 3 * 1024 * 1024);
  bf16*  kb  = (bf16*)(ws + (size_t) 4 * 1024 * 1024);
  bf16*  vb  = (bf16*)(ws + (size_t) 5 * 1024 * 1024);
  bf16*  ffb = (bf16*)(ws + (size_t) 6 * 1024 * 1024);
  float* fp  = ws + (size_t)2 * 1024 * 1024;          // 2 partials, 2M f32 each
  bf16*  lwb = (bf16*)(ws + (size_t)10 * 1024 * 1024);
  bf16*  xb  = (bf16*)(ws + (size_t)16 * 1024 * 1024);
  bf16*  pwb = (bf16*)ws;
  bf16*  wqt = lwb;
  bf16*  wkt = lwb + (size_t)1 * 1024 * 1024;
  bf16*  wvt = lwb + (size_t)2 * 1024 * 1024;
  bf16*  w1t = lwb + (size_t)3 * 1024 * 1024;
  bf16*  w2t = lwb + (size_t)7 * 1024 * 1024;

  embed_kernel<<<BT_, 256, 0, stream>>>(ids, emb, pos, x);

  for (int l = 0; l < L_; ++l) {
    const size_t lEE = (size_t)l * E_ * E_;
    const size_t lEF = (size_t)l * E_ * FF_;

    convw_kernel<<<dim3(E_/32, E_/32, 3), 256, 0, stream>>>(
        wq + lEE, wk + lEE, wv + lEE, wqt, wkt, wvt, E_, E_);
    convw_kernel<<<dim3(FF_/32, E_/32, 1), 256, 0, stream>>>(
        w1 + lEF, nullptr, nullptr, w1t, nullptr, nullptr, E_, FF_);
    convw_kernel<<<dim3(E_/32, FF_/32, 1), 256, 0, stream>>>(
        w2 + lEF, nullptr, nullptr, w2t, nullptr, nullptr, FF_, E_);

    ln_kernel<<<BT_, 256, 0, stream>>>(x, ln1g + l*E_, ln1b + l*E_, hb);

    gemm_bf16<0,1><<<dim3(16, E_/128, 3), 256, 0, stream>>>(
        hb, wqt, wkt, wvt, bq + l*E_, bk + l*E_, bv + l*E_,
        qb, kb, vb, nullptr, nullptr, E_, E_, E_);

    attn_kernel<<<dim3(T_/64, B_*H_), 256, 0, stream>>>(qb, kb, vb, x);

    ln_kernel<<<BT_, 256, 0, stream>>>(x, ln2g + l*E_, ln2b + l*E_, hb);

    gemm_bf16<1,1><<<dim3(16, FF_/128, 1), 256, 0, stream>>>(
        hb, w1t, nullptr, nullptr, b1 + (size_t)l*FF_, nullptr, nullptr,
        ffb, nullptr, nullptr, nullptr, nullptr, E_, FF_, E_);

    // FFN2: split-K=2 over blockIdx.z -> 256 blocks (full GPU), then combine
    gemm_bf16<0,3><<<dim3(16, E_/128, 2), 256, 0, stream>>>(
        ffb, w2t, nullptr, nullptr, nullptr, nullptr, nullptr,
        nullptr, nullptr, nullptr, fp, nullptr, FF_/2, E_, FF_);
    combine_kernel<<<BT_, 256, 0, stream>>>(fp, b2 + l*E_, x, xb);
  }

  // final projection: whole weight converted, 256^2 deep-pipelined GEMM
  convw_kernel<<<dim3(V_/32, E_/32, 1), 256, 0, stream>>>(
      pw, nullptr, nullptr, pwb, nullptr, nullptr, E_, V_);
  gemm256_kernel<<<(V_/256) * 8, 512, 0, stream>>>(
      xb, pwb, pb, out, E_, V_);
}